// Round 2
// baseline (2511.884 us; speedup 1.0000x reference)
//
#include <hip/hip_runtime.h>

typedef unsigned int uint;
typedef unsigned short ushort_t;
typedef float f32x4 __attribute__((ext_vector_type(4)));
typedef int i32x4 __attribute__((ext_vector_type(4)));

#define E_EXP 8
#define T_TOK 512
#define TOPK 2
#define A_ROWS 1024
#define H_DIM 2880
#define N1 5760
#define N2 2880
#define KDIM 2880
#define BM 128
#define BN 128
#define BK 64
#define LDS_STRIDE 72   // 64 + 8 pad (ushort elems), 144B row stride
#define MT_MAX 8

// ---------- numerics helpers ----------
__device__ inline unsigned short f32_bf16(float f){
  uint u = __float_as_uint(f);
  return (unsigned short)((u + 0x7FFFu + ((u >> 16) & 1u)) >> 16);
}

// RNE round-trip through fp8 e4m3fn; valid for |x| <= 448
__device__ inline float fp8_rt(float x){
  float ax = fabsf(x);
  if (ax < 0.03125f) return rintf(x * 512.0f) * 0.001953125f;  // denorm/low-exp grid 2^-9
  uint u = __float_as_uint(x);
  u = (u + 0x7FFFFu + ((u >> 20) & 1u)) & 0xFFF00000u;          // RNE to 3 mantissa bits
  return __uint_as_float(u);
}

// UE8M0 scale: maxv/448 rounded UP to power of 2 (bit trick identical to reference)
__device__ inline float ue8m0_scale(float maxv){
  float ds = maxv * (1.0f / 448.0f);
  uint di = (__float_as_uint(ds) + 0x7FFFFFu) & 0x7F800000u;
  float dr = __uint_as_float(di);
  if (dr == 0.0f) dr = 1.1754944e-38f;
  return dr;
}

// ---------- kernel 0: zero output ----------
__global__ void zero_f32(float4* p, int n4){
  int i = blockIdx.x * 256 + threadIdx.x;
  if (i < n4) p[i] = make_float4(0.f, 0.f, 0.f, 0.f);
}

// ---------- kernel 1: route sort (1 block) ----------
__global__ void route_sort(const int* __restrict__ ri, int* __restrict__ rows, int* __restrict__ offs){
  __shared__ int cnt[E_EXP], cur[E_EXP], base[E_EXP + 1];
  int tid = threadIdx.x;
  if (tid < E_EXP) cnt[tid] = 0;
  __syncthreads();
  int ev[4];
  #pragma unroll
  for (int i = 0; i < 4; i++){
    int it = tid + i * 256;
    ev[i] = ri[it];
    atomicAdd(&cnt[ev[i]], 1);
  }
  __syncthreads();
  if (tid == 0){
    int s = 0;
    for (int e = 0; e < E_EXP; e++){ base[e] = s; cur[e] = s; s += cnt[e]; }
    base[E_EXP] = s;
  }
  __syncthreads();
  if (tid <= E_EXP) offs[tid] = base[tid];
  #pragma unroll
  for (int i = 0; i < 4; i++){
    int it = tid + i * 256;
    int pos = atomicAdd(&cur[ev[i]], 1);
    rows[pos] = it;
  }
}

// ---------- kernel 2: quant-dequant hidden -> bf16 ----------
// 4 lanes per 32-elem block, 8 elems/lane. grid: T*H/32*4/256 = 720 blocks
__global__ void qd_hidden(const float* __restrict__ hs, ushort_t* __restrict__ xq){
  int g = blockIdx.x * 256 + threadIdx.x;
  int b = g >> 2, l4 = g & 3;
  int row = b / (H_DIM / 32), cb = b % (H_DIM / 32);
  const float* p = hs + (size_t)row * H_DIM + cb * 32 + l4 * 8;
  float4 v0 = ((const float4*)p)[0];
  float4 v1 = ((const float4*)p)[1];
  float vv[8] = {v0.x, v0.y, v0.z, v0.w, v1.x, v1.y, v1.z, v1.w};
  float am = 0.f;
  #pragma unroll
  for (int j = 0; j < 8; j++) am = fmaxf(am, fabsf(vv[j]));
  am = fmaxf(am, __shfl_xor(am, 1));
  am = fmaxf(am, __shfl_xor(am, 2));
  float dr = ue8m0_scale(am);
  float inv = 1.0f / dr;  // dr is power of 2 -> exact
  uint o[4];
  #pragma unroll
  for (int j = 0; j < 4; j++){
    float qa = fminf(fmaxf(vv[2*j]   * inv, -448.f), 448.f);
    float qb = fminf(fmaxf(vv[2*j+1] * inv, -448.f), 448.f);
    float ra = fp8_rt(qa) * dr;
    float rb = fp8_rt(qb) * dr;
    o[j] = (uint)f32_bf16(ra) | ((uint)f32_bf16(rb) << 16);
  }
  uint4* op = (uint4*)(xq + (size_t)row * H_DIM + cb * 32 + l4 * 8);
  *op = make_uint4(o[0], o[1], o[2], o[3]);
}

// ---------- kernel 4: swiglu + quant-dequant -> bf16 ----------
// 4 lanes per 32-output block (64 gu inputs), 16 gu / 8 out per lane. grid 1440
__global__ void swiglu_qd(const float* __restrict__ gu, ushort_t* __restrict__ iq){
  int g = blockIdx.x * 256 + threadIdx.x;
  int b = g >> 2, l4 = g & 3;
  int row = b / (N2 / 32), cb = b % (N2 / 32);
  const float* p = gu + (size_t)row * N1 + cb * 64 + l4 * 16;
  float x[16];
  #pragma unroll
  for (int i = 0; i < 4; i++){
    float4 v = ((const float4*)p)[i];
    x[4*i] = v.x; x[4*i+1] = v.y; x[4*i+2] = v.z; x[4*i+3] = v.w;
  }
  float vv[8];
  #pragma unroll
  for (int j = 0; j < 8; j++){
    float gate = fminf(x[2*j], 7.0f);
    float up   = fminf(fmaxf(x[2*j+1], -7.0f), 7.0f);
    float sg   = gate / (1.0f + expf(-1.702f * gate));
    vv[j] = sg * (up + 1.0f);
  }
  float am = 0.f;
  #pragma unroll
  for (int j = 0; j < 8; j++) am = fmaxf(am, fabsf(vv[j]));
  am = fmaxf(am, __shfl_xor(am, 1));
  am = fmaxf(am, __shfl_xor(am, 2));
  float dr = ue8m0_scale(am);
  float inv = 1.0f / dr;
  uint o[4];
  #pragma unroll
  for (int j = 0; j < 4; j++){
    float qa = fminf(fmaxf(vv[2*j]   * inv, -448.f), 448.f);
    float qb = fminf(fmaxf(vv[2*j+1] * inv, -448.f), 448.f);
    o[j] = (uint)f32_bf16(fp8_rt(qa) * dr) | ((uint)f32_bf16(fp8_rt(qb) * dr) << 16);
  }
  uint4* op = (uint4*)(iq + (size_t)row * N2 + cb * 32 + l4 * 8);
  *op = make_uint4(o[0], o[1], o[2], o[3]);
}

// ---------- grouped GEMM (MODE 1: gate_up -> gu f32; MODE 2: down -> atomicAdd out) ----------
template<int MODE>
__launch_bounds__(256, 2)
__global__ void gemm_grouped(const ushort_t* __restrict__ Amat, const float* __restrict__ W,
                             const float* __restrict__ bias, const int* __restrict__ rows,
                             const int* __restrict__ offs, float* __restrict__ outp,
                             const float* __restrict__ rwf){
  constexpr int N  = (MODE == 1) ? N1 : N2;
  constexpr int NT = (MODE == 1) ? (N1 / BN) : ((N2 + BN - 1) / BN);

  const int tid = threadIdx.x;
  const int lane = tid & 63;
  const int wv = tid >> 6;
  const int wm = wv >> 1, wn = wv & 1;

  int bx = blockIdx.x;
  const int e = bx / (MT_MAX * NT);
  int r2 = bx % (MT_MAX * NT);
  const int nt = r2 / MT_MAX;
  const int mt = r2 % MT_MAX;          // mt fastest -> same B panel adjacent
  const int off_e = offs[e];
  const int Me = offs[e + 1] - off_e;
  const int m0 = mt * BM;
  if (m0 >= Me) return;
  const int n0 = nt * BN;

  __shared__ __align__(16) ushort_t As[BM * LDS_STRIDE];
  __shared__ __align__(16) ushort_t Bs[BN * LDS_STRIDE];
  __shared__ int rows_s[BM];

  if (tid < BM){
    int mi = m0 + tid;
    if (mi >= Me) mi = Me - 1;
    rows_s[tid] = rows[off_e + mi];
  }
  __syncthreads();

  const float* We = W + (size_t)e * N * KDIM;

  // staging coords: each thread owns one A row-half and one B row-half
  const int ra = tid >> 1;
  const int ca = (tid & 1) * 4;                 // chunk base (8 bf16 each)
  int arow = rows_s[ra];
  if (MODE == 1) arow >>= 1;                    // assignment -> token
  const ushort_t* aptr = Amat + (size_t)arow * KDIM + ca * 8;
  const int rb = tid >> 1;
  int brow = n0 + rb;
  if (brow >= N) brow = N - 1;
  const float* bptr = We + (size_t)brow * KDIM + (tid & 1) * 32;

  uint4 aR[4];
  float4 bR[8];

  f32x4 acc[4][4];
  #pragma unroll
  for (int i = 0; i < 4; i++)
    #pragma unroll
    for (int j = 0; j < 4; j++)
      acc[i][j] = (f32x4){0.f, 0.f, 0.f, 0.f};

  // prologue load k-tile 0
  #pragma unroll
  for (int i = 0; i < 4; i++) aR[i] = *reinterpret_cast<const uint4*>(aptr + i * 8);
  #pragma unroll
  for (int i = 0; i < 8; i++) bR[i] = *reinterpret_cast<const float4*>(bptr + i * 4);

  const int KT = KDIM / BK;   // 45
  for (int kt = 0; kt < KT; ++kt){
    __syncthreads();
    // write staged regs -> LDS (fp32 -> bf16 for B)
    {
      ushort_t* aw = &As[ra * LDS_STRIDE + ca * 8];
      #pragma unroll
      for (int i = 0; i < 4; i++) *reinterpret_cast<uint4*>(aw + i * 8) = aR[i];
      ushort_t* bw = &Bs[rb * LDS_STRIDE + (tid & 1) * 32];
      #pragma unroll
      for (int i = 0; i < 4; i++){
        float4 xx = bR[2*i], yy = bR[2*i+1];
        uint4 o;
        o.x = (uint)f32_bf16(xx.x) | ((uint)f32_bf16(xx.y) << 16);
        o.y = (uint)f32_bf16(xx.z) | ((uint)f32_bf16(xx.w) << 16);
        o.z = (uint)f32_bf16(yy.x) | ((uint)f32_bf16(yy.y) << 16);
        o.w = (uint)f32_bf16(yy.z) | ((uint)f32_bf16(yy.w) << 16);
        *reinterpret_cast<uint4*>(bw + i * 8) = o;
      }
    }
    __syncthreads();
    // async-issue next tile's global loads (hide under MFMA phase)
    if (kt + 1 < KT){
      int k0 = (kt + 1) * BK;
      #pragma unroll
      for (int i = 0; i < 4; i++) aR[i] = *reinterpret_cast<const uint4*>(aptr + k0 + i * 8);
      #pragma unroll
      for (int i = 0; i < 8; i++) bR[i] = *reinterpret_cast<const float4*>(bptr + k0 + i * 4);
    }
    // compute current tile
    const ushort_t* Abase = &As[(wm * 64 + (lane & 15)) * LDS_STRIDE + ((lane >> 4) * 8)];
    const ushort_t* Bbase = &Bs[(wn * 64 + (lane & 15)) * LDS_STRIDE + ((lane >> 4) * 8)];
    #pragma unroll
    for (int ks = 0; ks < 2; ++ks){
      i32x4 af[4], bf[4];
      #pragma unroll
      for (int i = 0; i < 4; i++)
        af[i] = *reinterpret_cast<const i32x4*>(Abase + i * 16 * LDS_STRIDE + ks * 32);
      #pragma unroll
      for (int i = 0; i < 4; i++)
        bf[i] = *reinterpret_cast<const i32x4*>(Bbase + i * 16 * LDS_STRIDE + ks * 32);
      #pragma unroll
      for (int mi = 0; mi < 4; mi++)
        #pragma unroll
        for (int ni = 0; ni < 4; ni++)
          asm volatile("v_mfma_f32_16x16x32_bf16 %0, %1, %2, %0"
                       : "+v"(acc[mi][ni]) : "v"(af[mi]), "v"(bf[ni]));
    }
  }
  asm volatile("s_nop 7\n\ts_nop 7\n\ts_nop 7" ::: "memory");

  // epilogue
  const int ln = lane & 15, lh = lane >> 4;
  const float* biasE = bias + (size_t)e * N;
  float bn[4];
  #pragma unroll
  for (int ni = 0; ni < 4; ni++){
    int n = n0 + wn * 64 + ni * 16 + ln;
    bn[ni] = (n < N) ? biasE[n] : 0.f;
  }
  #pragma unroll
  for (int mi = 0; mi < 4; mi++){
    #pragma unroll
    for (int rr = 0; rr < 4; rr++){
      int m = wm * 64 + mi * 16 + lh * 4 + rr;
      if (m0 + m < Me){
        int aid = rows_s[m];
        if (MODE == 1){
          float* gp = outp + (size_t)aid * N1 + n0 + wn * 64 + ln;
          #pragma unroll
          for (int ni = 0; ni < 4; ni++) gp[ni * 16] = acc[mi][ni][rr] + bn[ni];
        } else {
          int t = aid >> 1;
          float w = rwf[aid];
          float* op = outp + (size_t)t * N2;
          #pragma unroll
          for (int ni = 0; ni < 4; ni++){
            int n = n0 + wn * 64 + ni * 16 + ln;
            if (n < N2) atomicAdd(op + n, w * (acc[mi][ni][rr] + bn[ni]));
          }
        }
      }
    }
  }
}

extern "C" void kernel_launch(void* const* d_in, const int* in_sizes, int n_in,
                              void* d_out, int out_size, void* d_ws, size_t ws_size,
                              hipStream_t stream) {
  const float* hs  = (const float*)d_in[0];
  const int*   ri  = (const int*)d_in[1];
  const float* rw  = (const float*)d_in[2];
  const float* gup = (const float*)d_in[3];
  const float* gub = (const float*)d_in[4];
  const float* dwn = (const float*)d_in[5];
  const float* dwb = (const float*)d_in[6];
  float* out = (float*)d_out;

  char* ws = (char*)d_ws;
  ushort_t* xq = (ushort_t*)ws;                                   // 512*2880*2  = 2,949,120
  ushort_t* iq = (ushort_t*)(ws + 2949120);                       // 1024*2880*2 = 5,898,240
  float*    gu = (float*)(ws + 2949120 + 5898240);                // 1024*5760*4 = 23,592,960
  int*    rows = (int*)(ws + 32440320);
  int*    offs = rows + A_ROWS;

  // 0: zero output (re-poisoned to 0xAA before every timed launch)
  zero_f32<<<(T_TOK * H_DIM / 4 + 255) / 256, 256, 0, stream>>>((float4*)out, T_TOK * H_DIM / 4);
  // 1: bucket assignments by expert
  route_sort<<<1, 256, 0, stream>>>(ri, rows, offs);
  // 2: quant-dequant hidden -> exact bf16
  qd_hidden<<<(T_TOK * H_DIM / 32 * 4) / 256, 256, 0, stream>>>(hs, xq);
  // 3: grouped GEMM1 (+bias) -> gu
  gemm_grouped<1><<<E_EXP * MT_MAX * (N1 / BN), 256, 0, stream>>>(xq, gup, gub, rows, offs, gu, nullptr);
  // 4: swiglu + quant-dequant -> exact bf16
  swiglu_qd<<<(A_ROWS * N2 / 32 * 4) / 256, 256, 0, stream>>>(gu, iq);
  // 5: grouped GEMM2 (+bias, *rw) -> scatter-add into out
  gemm_grouped<2><<<E_EXP * MT_MAX * ((N2 + BN - 1) / BN), 256, 0, stream>>>(iq, dwn, dwb, rows, offs, out, rw);
}